// Round 21
// baseline (6579.470 us; speedup 1.0000x reference)
//
#include <hip/hip_runtime.h>

// All ops except the two deliberate FMAs below are per-op rounded.
#pragma clang fp contract(off)

#define BATCH 32
#define NPTS 100000
#define NGROUP 2048
#define NBLK_PER_BATCH 8
#define NPB (NPTS / NBLK_PER_BATCH)   /* 12500 points per block */
#define TPB 512
#define NPT 25                        /* ceil(12500/512) points per thread */
#define TAIL (NPB - (NPT - 1) * TPB)  /* 212 */

typedef unsigned long long u64;
typedef unsigned int u32;

static_assert(NPB * NBLK_PER_BATCH == NPTS, "block split must be exact");
static_assert(NPT * TPB >= NPB, "per-thread capacity");

// Guaranteed single-instruction IEEE ops (immune to compiler contraction
// decisions in either direction).
__device__ __forceinline__ float fsub_x(float a, float b) {
  float r; asm("v_sub_f32 %0, %1, %2" : "=v"(r) : "v"(a), "v"(b)); return r;
}
__device__ __forceinline__ float fmul_x(float a, float b) {
  float r; asm("v_mul_f32 %0, %1, %2" : "=v"(r) : "v"(a), "v"(b)); return r;
}
__device__ __forceinline__ float fma_x(float a, float b, float c) {
  float r; asm("v_fma_f32 %0, %1, %2, %3" : "=v"(r) : "v"(a), "v"(b), "v"(c)); return r;
}

#define LD_WG(p)    __hip_atomic_load((p),  __ATOMIC_RELAXED, __HIP_MEMORY_SCOPE_WORKGROUP)
#define ST_WG(p,v)  __hip_atomic_store((p), (v), __ATOMIC_RELAXED, __HIP_MEMORY_SCOPE_WORKGROUP)
#define LD_AG(p)    __hip_atomic_load((p),  __ATOMIC_RELAXED, __HIP_MEMORY_SCOPE_AGENT)
#define ST_AG(p,v)  __hip_atomic_store((p), (v), __ATOMIC_RELAXED, __HIP_MEMORY_SCOPE_AGENT)

// Packed candidate: distbits[63:32] | tag[31:17] | ~idx[16:0]; ~idx makes
// u64-max pick the LOWEST index on ties. All handshakes tagged +
// parity-double-buffered (init tag 0x7FFF never matches t <= 2046).
//
// R20 lesson: coordination hops, not compute/coord-fetch, dominate the
// 2.6 us serial iteration. This round removes the srel release stage: ALL
// waves poll the batch's 64B global slot line directly (8 lanes each),
// reduce, and prefetch winner coords themselves. LDS spin traffic shrinks to
// wid0's 8-lane sval gather, de-contending the LDS coord reads.
// (R14's blowup was 64 publishers + 64x64-lane polling; here: 8 publishers,
// 64x8-lane polling on one line — 8x lighter, FETCH_SIZE is the tripwire.)
__global__ __launch_bounds__(TPB, 1)
void fps_kernel(const float* __restrict__ xyz,
                const int* __restrict__ finit,
                float* __restrict__ out,
                u64* __restrict__ slots)
{
  const int blk  = blockIdx.x;
  const int b    = blk & (BATCH - 1);   // batch id
  const int j    = blk >> 5;            // sub-block 0..7 within batch
  const int tid  = threadIdx.x;
  const int lane = tid & 63;
  const int wid  = tid >> 6;

  __shared__ float sx[NPB], sy[NPB], sz[NPB];   // 150,000 B coord planes
  __shared__ u64 sval[2][8];   // [parity][wave] tagged candidates

  // invalidate LDS tags (0x7FFF)
  if (tid < 16) sval[tid >> 3][tid & 7] = ~0ull;

  const float* xb = xyz + (size_t)b * NPTS * 3;
  const int base = j * NPB;

  // stage this block's 12500-point coord slice into LDS (once) and init the
  // register-resident running min distance
  float pd[NPT];
#pragma unroll
  for (int i = 0; i < NPT; ++i) {
    const bool valid = (i < NPT - 1) || (tid < TAIL);
    const int p = tid + i * TPB;
    if (valid) {
      const int gp = base + p;
      sx[p] = xb[gp * 3 + 0];
      sy[p] = xb[gp * 3 + 1];
      sz[p] = xb[gp * 3 + 2];
    }
    pd[i] = valid ? 1.0e10f : -1.0f;   // invalid pads can never win argmax
  }
  __syncthreads();   // the only barrier: LDS coords + tags ready

  const int cur0 = finit[b];   // int32 delivery (established R8==R5, R1==R2)
  float cx = xb[cur0 * 3 + 0], cy = xb[cur0 * 3 + 1], cz = xb[cur0 * 3 + 2];

  u64* gs = slots + (size_t)b * 2 * NBLK_PER_BATCH;   // [parity][block], 64B/parity

  for (int t = 0; t < NGROUP; ++t) {
    // record current farthest (pre-update); wid1 keeps this off wave 0's path
    if (j == 0 && wid == 1 && lane == 0) {
      float* o = out + ((size_t)b * NGROUP + t) * 3;
      o[0] = cx; o[1] = cy; o[2] = cz;
    }
    if (t == NGROUP - 1) break;   // uniform exit

    const int p   = t & 1;
    const u32 tag = (u32)(t & 0x7FFF);

    // --- distance min-update + thread-local argmax (first-max wins) ---
    float bestv = -1.0f;
    int   besti = 0x7fffffff;
#pragma unroll
    for (int i = 0; i < NPT; ++i) {
      const bool valid = (i < NPT - 1) || (tid < TAIL);
      const int  pp = tid + i * TPB;
      const float dx = fsub_x(sx[pp], cx);
      const float dy = fsub_x(sy[pp], cy);
      const float dz = fsub_x(sz[pp], cz);
      const float d  = fma_x(dz, dz, fma_x(dy, dy, fmul_x(dx, dx)));   // XLA-contracted (R12-verified)
      if (valid) {
        const float nd = fminf(pd[i], d);   // jnp.minimum
        pd[i] = nd;
        if (nd > bestv) { bestv = nd; besti = base + pp; }  // strict >: lowest idx
      }
    }

    // --- wave-level u64-max reduce ---
    u64 pk = ((u64)__float_as_uint(bestv) << 32) | (u64)((~(u32)besti) & 0x1FFFFu);
#pragma unroll
    for (int off = 32; off > 0; off >>= 1) {
      const u64 o = __shfl_xor(pk, off, 64);
      if (o > pk) pk = o;
    }
    if (lane == 0) ST_WG(&sval[p][wid], pk | ((u64)tag << 17));

    if (wid == 0) {
      // --- gather the 8 wave candidates via tagged-LDS spin (no barrier) ---
      u64 sv;
      do {
        sv = (lane < 8) ? LD_WG(&sval[p][lane]) : 0ull;
      } while (!__all(lane >= 8 || (((u32)(sv >> 17) & 0x7FFFu) == tag)));
#pragma unroll
      for (int off = 4; off > 0; off >>= 1) {
        const u64 o = __shfl_xor(sv, off, 64);
        if (o > sv) sv = o;
      }
      // --- publish block candidate ---
      if (lane == 0) ST_AG(gs + p * NBLK_PER_BATCH + j, sv);
    }

    // --- ALL waves: poll the batch's 64B slot line directly ---
    u64 gv;
    do {
      gv = (lane < NBLK_PER_BATCH) ? LD_AG(gs + p * NBLK_PER_BATCH + lane) : 0ull;
    } while (!__all(lane >= NBLK_PER_BATCH || (((u32)(gv >> 17) & 0x7FFFu) == tag)));

    // --- speculative coord prefetch for all 8 candidates (hides the
    //     dependent centroid load under the final reduce) ---
    float fx = 0.f, fy = 0.f, fz = 0.f;
    if (lane < NBLK_PER_BATCH) {
      const int cand = (int)((~(u32)gv) & 0x1FFFFu);
      const float* cp = xb + (size_t)cand * 3;
      fx = cp[0]; fy = cp[1]; fz = cp[2];
    }
    u64 win = gv;   // lanes >= 8 hold 0 (can never win: ~idx low bits > 0)
#pragma unroll
    for (int off = 4; off > 0; off >>= 1) {
      const u64 o = __shfl_xor(win, off, 64);
      if (o > win) win = o;
    }
    const u64 wmax = __shfl(win, 0, 64);
    const u64 mask = __ballot(lane < NBLK_PER_BATCH && gv == wmax);
    const int w    = (int)__ffsll((long long)mask) - 1;
    cx = __shfl(fx, w, 64); cy = __shfl(fy, w, 64); cz = __shfl(fz, w, 64);
  }
}

extern "C" void kernel_launch(void* const* d_in, const int* in_sizes, int n_in,
                              void* d_out, int out_size, void* d_ws, size_t ws_size,
                              hipStream_t stream) {
  const float* xyz   = (const float*)d_in[0];
  const int*   finit = (const int*)d_in[1];
  float*       out   = (float*)d_out;
  u64*         slots = (u64*)d_ws;   // 32 x 2 x 8 u64 = 4 KB exchange slots

  // Invalidate all global slots every call (tag -> 0x7FFF, never valid).
  hipMemsetAsync(d_ws, 0xFF,
                 (size_t)BATCH * 2 * NBLK_PER_BATCH * sizeof(u64), stream);

  fps_kernel<<<dim3(BATCH * NBLK_PER_BATCH), dim3(TPB), 0, stream>>>(xyz, finit, out, slots);
}

// Round 23
// 5012.398 us; speedup vs baseline: 1.3126x; 1.3126x over previous
//
#include <hip/hip_runtime.h>

// All ops except the two deliberate FMAs below are per-op rounded.
#pragma clang fp contract(off)

#define BATCH 32
#define NPTS 100000
#define NGROUP 2048
#define NBLK_PER_BATCH 8
#define NPB (NPTS / NBLK_PER_BATCH)   /* 12500 points per block */
#define TPB 512
#define NPT 25                        /* ceil(12500/512) points per thread */
#define TAIL (NPB - (NPT - 1) * TPB)  /* 212 */

typedef unsigned long long u64;
typedef unsigned int u32;

static_assert(NPB * NBLK_PER_BATCH == NPTS, "block split must be exact");
static_assert(NPT * TPB >= NPB, "per-thread capacity");

// Guaranteed single-instruction IEEE ops (immune to compiler contraction
// decisions in either direction).
__device__ __forceinline__ float fsub_x(float a, float b) {
  float r; asm("v_sub_f32 %0, %1, %2" : "=v"(r) : "v"(a), "v"(b)); return r;
}
__device__ __forceinline__ float fmul_x(float a, float b) {
  float r; asm("v_mul_f32 %0, %1, %2" : "=v"(r) : "v"(a), "v"(b)); return r;
}
__device__ __forceinline__ float fma_x(float a, float b, float c) {
  float r; asm("v_fma_f32 %0, %1, %2, %3" : "=v"(r) : "v"(a), "v"(b), "v"(c)); return r;
}

#define LD_AG(p)    __hip_atomic_load((p),  __ATOMIC_RELAXED, __HIP_MEMORY_SCOPE_AGENT)
#define ST_AG(p,v)  __hip_atomic_store((p), (v), __ATOMIC_RELAXED, __HIP_MEMORY_SCOPE_AGENT)

// Synthesis of R16/R20/R21:
//  - coords staged in LDS (150,000 B) -> compute phase reads LDS, not L2
//    (L2 restream was ~2700 cyc of the 5800-cyc iteration in R16)
//  - intra-block sync via HW barriers, NOT LDS spins: waves waiting in
//    s_barrier consume zero LDS bandwidth (R20's LDS-spin waves starved the
//    LDS-resident compute -> regression)
//  - global exchange unchanged from R16: 8 tagged parity slots/batch,
//    published and polled by wid0 only (R14/R21: wider polling explodes
//    coherence traffic)
// sval/scoord are barrier-separated -> no tags/parity needed intra-block.
// Global slots: distbits[63:32] | tag[31:17] | ~idx[16:0]; ~idx -> lowest
// index wins ties; memset 0xFF per call (tag 0x7FFF never matches t<=2046).
__global__ __launch_bounds__(TPB, 1)
void fps_kernel(const float* __restrict__ xyz,
                const int* __restrict__ finit,
                float* __restrict__ out,
                u64* __restrict__ slots)
{
  const int blk  = blockIdx.x;
  const int b    = blk & (BATCH - 1);   // batch id
  const int j    = blk >> 5;            // sub-block 0..7 within batch
  const int tid  = threadIdx.x;
  const int lane = tid & 63;
  const int wid  = tid >> 6;

  __shared__ float sx[NPB], sy[NPB], sz[NPB];   // 150,000 B coord planes
  __shared__ u64   sval[8];     // per-wave candidates (barrier-separated)
  __shared__ float scoord[3];   // winner coords (barrier-separated)

  const float* xb = xyz + (size_t)b * NPTS * 3;
  const int base = j * NPB;

  // stage this block's 12500-point coord slice into LDS (once) and init the
  // register-resident running min distance
  float pd[NPT];
#pragma unroll
  for (int i = 0; i < NPT; ++i) {
    const bool valid = (i < NPT - 1) || (tid < TAIL);
    const int p = tid + i * TPB;
    if (valid) {
      const int gp = base + p;
      sx[p] = xb[gp * 3 + 0];
      sy[p] = xb[gp * 3 + 1];
      sz[p] = xb[gp * 3 + 2];
    }
    pd[i] = valid ? 1.0e10f : -1.0f;   // invalid pads can never win argmax
  }
  __syncthreads();   // LDS coords ready

  const int cur0 = finit[b];   // int32 delivery (established R8==R5, R1==R2)
  float cx = xb[cur0 * 3 + 0], cy = xb[cur0 * 3 + 1], cz = xb[cur0 * 3 + 2];

  u64* gs = slots + (size_t)b * 2 * NBLK_PER_BATCH;   // [parity][block], 64B/parity

  for (int t = 0; t < NGROUP; ++t) {
    // record current farthest (pre-update); off wave 0's critical path
    if (j == 0 && wid == 1 && lane == 0) {
      float* o = out + ((size_t)b * NGROUP + t) * 3;
      o[0] = cx; o[1] = cy; o[2] = cz;
    }
    if (t == NGROUP - 1) break;   // uniform exit

    const int p   = t & 1;
    const u32 tag = (u32)(t & 0x7FFF);

    // --- distance min-update + thread-local argmax (first-max wins) ---
    float bestv = -1.0f;
    int   besti = 0x7fffffff;
#pragma unroll
    for (int i = 0; i < NPT; ++i) {
      const bool valid = (i < NPT - 1) || (tid < TAIL);
      const int  pp = tid + i * TPB;
      const float dx = fsub_x(sx[pp], cx);
      const float dy = fsub_x(sy[pp], cy);
      const float dz = fsub_x(sz[pp], cz);
      const float d  = fma_x(dz, dz, fma_x(dy, dy, fmul_x(dx, dx)));   // XLA-contracted (R12-verified)
      if (valid) {
        const float nd = fminf(pd[i], d);   // jnp.minimum
        pd[i] = nd;
        if (nd > bestv) { bestv = nd; besti = base + pp; }  // strict >: lowest idx
      }
    }

    // --- wave-level u64-max reduce, post to LDS ---
    u64 pk = ((u64)__float_as_uint(bestv) << 32) | (u64)((~(u32)besti) & 0x1FFFFu);
#pragma unroll
    for (int off = 32; off > 0; off >>= 1) {
      const u64 o = __shfl_xor(pk, off, 64);
      if (o > pk) pk = o;
    }
    if (lane == 0) sval[wid] = pk;
    __syncthreads();   // candidates posted; waiting waves use no LDS BW

    if (wid == 0) {
      // --- reduce 8 wave candidates ---
      u64 sv = (lane < 8) ? sval[lane] : 0ull;
#pragma unroll
      for (int off = 4; off > 0; off >>= 1) {
        const u64 o = __shfl_xor(sv, off, 64);
        if (o > sv) sv = o;
      }
      // --- publish block candidate, poll the batch's 64B slot line ---
      if (lane == 0) ST_AG(gs + p * NBLK_PER_BATCH + j, sv | ((u64)tag << 17));
      u64 gv;
      do {
        gv = (lane < NBLK_PER_BATCH) ? LD_AG(gs + p * NBLK_PER_BATCH + lane) : 0ull;
      } while (!__all(lane >= NBLK_PER_BATCH || (((u32)(gv >> 17) & 0x7FFFu) == tag)));

      // --- speculative coord prefetch for all 8 candidates (hides the
      //     dependent centroid load under the final reduce) ---
      float fx = 0.f, fy = 0.f, fz = 0.f;
      if (lane < NBLK_PER_BATCH) {
        const int cand = (int)((~(u32)gv) & 0x1FFFFu);
        const float* cp = xb + (size_t)cand * 3;
        fx = cp[0]; fy = cp[1]; fz = cp[2];
      }
      u64 win = gv;   // lanes >= 8 hold 0 (can never win: ~idx low bits > 0)
#pragma unroll
      for (int off = 4; off > 0; off >>= 1) {
        const u64 o = __shfl_xor(win, off, 64);
        if (o > win) win = o;
      }
      const u64 wmax = __shfl(win, 0, 64);
      const u64 mask = __ballot(lane < NBLK_PER_BATCH && gv == wmax);
      const int w    = (int)__ffsll((long long)mask) - 1;
      const float ncx = __shfl(fx, w, 64);
      const float ncy = __shfl(fy, w, 64);
      const float ncz = __shfl(fz, w, 64);
      if (lane == 0) { scoord[0] = ncx; scoord[1] = ncy; scoord[2] = ncz; }
    }
    __syncthreads();   // winner coords ready

    cx = scoord[0]; cy = scoord[1]; cz = scoord[2];
  }
}

extern "C" void kernel_launch(void* const* d_in, const int* in_sizes, int n_in,
                              void* d_out, int out_size, void* d_ws, size_t ws_size,
                              hipStream_t stream) {
  const float* xyz   = (const float*)d_in[0];
  const int*   finit = (const int*)d_in[1];
  float*       out   = (float*)d_out;
  u64*         slots = (u64*)d_ws;   // 32 x 2 x 8 u64 = 4 KB exchange slots

  // Invalidate all global slots every call (tag -> 0x7FFF, never valid).
  hipMemsetAsync(d_ws, 0xFF,
                 (size_t)BATCH * 2 * NBLK_PER_BATCH * sizeof(u64), stream);

  fps_kernel<<<dim3(BATCH * NBLK_PER_BATCH), dim3(TPB), 0, stream>>>(xyz, finit, out, slots);
}

// Round 24
// 4992.426 us; speedup vs baseline: 1.3179x; 1.0040x over previous
//
#include <hip/hip_runtime.h>

// All ops except the two deliberate FMAs below are per-op rounded.
#pragma clang fp contract(off)

#define BATCH 32
#define NPTS 100000
#define NGROUP 2048
#define NBLK_PER_BATCH 8
#define NPB (NPTS / NBLK_PER_BATCH)   /* 12500 points per block */
#define TPB 512
#define NPT 25                        /* staging: ceil(12500/512) writes/thread */
#define TAIL (NPB - (NPT - 1) * TPB)  /* 212 */
#define NQUAD 7                       /* compute: quads of 4 consecutive pts */
#define QTOT (NPB / 4)                /* 3125 quads, exact */
#define QTAIL (QTOT - (NQUAD - 1) * TPB) /* 53: threads < 53 own a 7th quad */

typedef unsigned long long u64;
typedef unsigned int u32;

static_assert(NPB * NBLK_PER_BATCH == NPTS, "block split must be exact");
static_assert(QTOT * 4 == NPB, "quad split must be exact");

// Guaranteed single-instruction IEEE ops (immune to compiler contraction
// decisions in either direction).
__device__ __forceinline__ float fsub_x(float a, float b) {
  float r; asm("v_sub_f32 %0, %1, %2" : "=v"(r) : "v"(a), "v"(b)); return r;
}
__device__ __forceinline__ float fmul_x(float a, float b) {
  float r; asm("v_mul_f32 %0, %1, %2" : "=v"(r) : "v"(a), "v"(b)); return r;
}
__device__ __forceinline__ float fma_x(float a, float b, float c) {
  float r; asm("v_fma_f32 %0, %1, %2, %3" : "=v"(r) : "v"(a), "v"(b), "v"(c)); return r;
}

#define LD_AG(p)    __hip_atomic_load((p),  __ATOMIC_RELAXED, __HIP_MEMORY_SCOPE_AGENT)
#define ST_AG(p,v)  __hip_atomic_store((p), (v), __ATOMIC_RELAXED, __HIP_MEMORY_SCOPE_AGENT)

// R23 post-mortem: coord reads were 75 ds_read_b32/thread = 600 wave-inst/CU
// x 5.8 cyc ~= 3500 cyc/iter of DS issue — as slow as the L2 restream it
// replaced. This round: quads of 4 consecutive points, 3 x ds_read_b128 per
// quad (16B-aligned), 21 DS inst/thread (168/CU ~= 2000 cyc). Validity via
// sentinel pd=-1 + clamped addresses (no per-point predication).
// Exchange protocol unchanged from R23 (tagged parity slots, wid0-only).
__global__ __launch_bounds__(TPB, 1)
void fps_kernel(const float* __restrict__ xyz,
                const int* __restrict__ finit,
                float* __restrict__ out,
                u64* __restrict__ slots)
{
  const int blk  = blockIdx.x;
  const int b    = blk & (BATCH - 1);   // batch id
  const int j    = blk >> 5;            // sub-block 0..7 within batch
  const int tid  = threadIdx.x;
  const int lane = tid & 63;
  const int wid  = tid >> 6;

  __shared__ __align__(16) float sx[NPB];   // 50,000 B per plane
  __shared__ __align__(16) float sy[NPB];
  __shared__ __align__(16) float sz[NPB];
  __shared__ u64   sval[8];     // per-wave candidates (barrier-separated)
  __shared__ float scoord[3];   // winner coords (barrier-separated)

  const float* xb = xyz + (size_t)b * NPTS * 3;
  const int base = j * NPB;

  // stage this block's 12500-point coord slice into LDS (once)
#pragma unroll
  for (int i = 0; i < NPT; ++i) {
    const bool valid = (i < NPT - 1) || (tid < TAIL);
    const int p = tid + i * TPB;
    if (valid) {
      const int gp = base + p;
      sx[p] = xb[gp * 3 + 0];
      sy[p] = xb[gp * 3 + 1];
      sz[p] = xb[gp * 3 + 2];
    }
  }
  // register-resident running min distance, quad layout; sentinel -1 for
  // slots beyond QTOT (they can never win argmax: strict > vs bestv >= -1)
  float pd[NQUAD * 4];
#pragma unroll
  for (int q = 0; q < NQUAD; ++q) {
    const bool vq = (q < NQUAD - 1) || (tid < QTAIL);
#pragma unroll
    for (int k = 0; k < 4; ++k) pd[q * 4 + k] = vq ? 1.0e10f : -1.0f;
  }
  __syncthreads();   // LDS coords ready

  const int cur0 = finit[b];   // int32 delivery (established R8==R5, R1==R2)
  float cx = xb[cur0 * 3 + 0], cy = xb[cur0 * 3 + 1], cz = xb[cur0 * 3 + 2];

  u64* gs = slots + (size_t)b * 2 * NBLK_PER_BATCH;   // [parity][block], 64B/parity

  for (int t = 0; t < NGROUP; ++t) {
    // record current farthest (pre-update); off wave 0's critical path
    if (j == 0 && wid == 1 && lane == 0) {
      float* o = out + ((size_t)b * NGROUP + t) * 3;
      o[0] = cx; o[1] = cy; o[2] = cz;
    }
    if (t == NGROUP - 1) break;   // uniform exit

    const int p   = t & 1;
    const u32 tag = (u32)(t & 0x7FFF);

    // --- distance min-update + thread-local argmax (first-max wins) ---
    float bestv = -1.0f;
    int   besti = 0x7fffffff;
#pragma unroll
    for (int q = 0; q < NQUAD; ++q) {
      int qi = tid + q * TPB;
      if (q == NQUAD - 1 && tid >= QTAIL) qi = 0;   // clamped; pd slots = -1
      const int pb = qi * 4;
      const float4 vx = *(const float4*)&sx[pb];    // ds_read_b128 x3
      const float4 vy = *(const float4*)&sy[pb];
      const float4 vz = *(const float4*)&sz[pb];
#define POINT(K, XK, YK, ZK)                                                  \
      {                                                                       \
        const float dx = fsub_x(XK, cx);                                      \
        const float dy = fsub_x(YK, cy);                                      \
        const float dz = fsub_x(ZK, cz);                                      \
        const float d  = fma_x(dz, dz, fma_x(dy, dy, fmul_x(dx, dx)));        \
        const float nd = fminf(pd[q * 4 + K], d);                             \
        pd[q * 4 + K] = nd;                                                   \
        if (nd > bestv) { bestv = nd; besti = base + pb + K; }                \
      }
      POINT(0, vx.x, vy.x, vz.x)
      POINT(1, vx.y, vy.y, vz.y)
      POINT(2, vx.z, vy.z, vz.z)
      POINT(3, vx.w, vy.w, vz.w)
#undef POINT
    }

    // --- wave-level u64-max reduce, post to LDS ---
    u64 pk = ((u64)__float_as_uint(bestv) << 32) | (u64)((~(u32)besti) & 0x1FFFFu);
#pragma unroll
    for (int off = 32; off > 0; off >>= 1) {
      const u64 o = __shfl_xor(pk, off, 64);
      if (o > pk) pk = o;
    }
    if (lane == 0) sval[wid] = pk;
    __syncthreads();   // candidates posted; waiting waves use no LDS BW

    if (wid == 0) {
      // --- reduce 8 wave candidates ---
      u64 sv = (lane < 8) ? sval[lane] : 0ull;
#pragma unroll
      for (int off = 4; off > 0; off >>= 1) {
        const u64 o = __shfl_xor(sv, off, 64);
        if (o > sv) sv = o;
      }
      // --- publish block candidate, poll the batch's 64B slot line ---
      if (lane == 0) ST_AG(gs + p * NBLK_PER_BATCH + j, sv | ((u64)tag << 17));
      u64 gv;
      do {
        gv = (lane < NBLK_PER_BATCH) ? LD_AG(gs + p * NBLK_PER_BATCH + lane) : 0ull;
      } while (!__all(lane >= NBLK_PER_BATCH || (((u32)(gv >> 17) & 0x7FFFu) == tag)));

      // --- speculative coord prefetch for all 8 candidates (hides the
      //     dependent centroid load under the final reduce) ---
      float fx = 0.f, fy = 0.f, fz = 0.f;
      if (lane < NBLK_PER_BATCH) {
        const int cand = (int)((~(u32)gv) & 0x1FFFFu);
        const float* cp = xb + (size_t)cand * 3;
        fx = cp[0]; fy = cp[1]; fz = cp[2];
      }
      u64 win = gv;   // lanes >= 8 hold 0 (can never win: ~idx low bits > 0)
#pragma unroll
      for (int off = 4; off > 0; off >>= 1) {
        const u64 o = __shfl_xor(win, off, 64);
        if (o > win) win = o;
      }
      const u64 wmax = __shfl(win, 0, 64);
      const u64 mask = __ballot(lane < NBLK_PER_BATCH && gv == wmax);
      const int w    = (int)__ffsll((long long)mask) - 1;
      const float ncx = __shfl(fx, w, 64);
      const float ncy = __shfl(fy, w, 64);
      const float ncz = __shfl(fz, w, 64);
      if (lane == 0) { scoord[0] = ncx; scoord[1] = ncy; scoord[2] = ncz; }
    }
    __syncthreads();   // winner coords ready

    cx = scoord[0]; cy = scoord[1]; cz = scoord[2];
  }
}

extern "C" void kernel_launch(void* const* d_in, const int* in_sizes, int n_in,
                              void* d_out, int out_size, void* d_ws, size_t ws_size,
                              hipStream_t stream) {
  const float* xyz   = (const float*)d_in[0];
  const int*   finit = (const int*)d_in[1];
  float*       out   = (float*)d_out;
  u64*         slots = (u64*)d_ws;   // 32 x 2 x 8 u64 = 4 KB exchange slots

  // Invalidate all global slots every call (tag -> 0x7FFF, never valid).
  hipMemsetAsync(d_ws, 0xFF,
                 (size_t)BATCH * 2 * NBLK_PER_BATCH * sizeof(u64), stream);

  fps_kernel<<<dim3(BATCH * NBLK_PER_BATCH), dim3(TPB), 0, stream>>>(xyz, finit, out, slots);
}